// Round 12
// baseline (398.727 us; speedup 1.0000x reference)
//
#include <hip/hip_runtime.h>

// Problem constants
#define BTOT 16384
#define NI   16
#define HD   256
#define BB   4            // elements per block = waves per block (waves independent)
#define NMID 3
#define ASH  264          // h LDS row stride in bf16 (528B: rows spread 4 banks apart)
#define SLS  20           // slater scratch row stride (floats)
#define HALF_LOGFACT 15.3359295387f  // 0.5 * ln(16!)

typedef short  bf16x8 __attribute__((ext_vector_type(8)));
typedef float  f32x4  __attribute__((ext_vector_type(4)));

__device__ __forceinline__ unsigned short f2bf(float f) {   // prep kernel only
    unsigned u = __builtin_bit_cast(unsigned, f);
    u += 0x7FFFu + ((u >> 16) & 1u);
    return (unsigned short)(u >> 16);
}
__device__ __forceinline__ unsigned cvt_pk_bf16(float lo, float hi) {
    unsigned d;
    asm("v_cvt_pk_bf16_f32 %0, %1, %2" : "=v"(d) : "v"(lo), "v"(hi));
    return d;   // d[15:0]=bf16(lo), d[31:16]=bf16(hi)
}
__device__ __forceinline__ float bflo(unsigned u) { return __builtin_bit_cast(float, u << 16); }
__device__ __forceinline__ float bfhi(unsigned u) { return __builtin_bit_cast(float, u & 0xFFFF0000u); }
__device__ __forceinline__ float bcast(float x, int lane) {
    return __builtin_bit_cast(float,
        __builtin_amdgcn_readlane(__builtin_bit_cast(int, x), lane));
}
// tanh(x) = 1 - 2/(1 + 2^(x*2*log2(e))) : 5 VALU ops
__device__ __forceinline__ float tanh5(float x) {
    float z = __builtin_amdgcn_exp2f(x * 2.885390081777927f);
    return __builtin_fmaf(-2.0f, __builtin_amdgcn_rcpf(1.0f + z), 1.0f);
}
// within-wave LDS ordering for cross-lane produce/consume (NOT a block barrier)
#define LGKM_WAIT() do { asm volatile("s_waitcnt lgkmcnt(0)" ::: "memory"); \
    __builtin_amdgcn_sched_barrier(0); } while (0)

// ---- prep: chunked fragment-order weights (verified R6-R11).
// Chunk fc<48: (layer=fc>>4, ch=fc&15): dst[kg*128 + j*8 + kk] = Wmid[layer][8kg+kk][ch*16+j],
//   kg in [0,64). Chunk 48: Wsl, kg in [0,32), rest zero.
__global__ void prep_w(const float* __restrict__ Wmid, const float* __restrict__ Wsl,
                       unsigned short* __restrict__ wtc) {
    const int b = blockIdx.x;       // 0..48
    const int t = threadIdx.x;
    unsigned short* dst = wtc + (size_t)b * 8192;
    if (b < 48) {
        const int layer = b >> 4, ch = b & 15;
        const float* src = Wmid + (size_t)layer * (2 * HD * HD);
#pragma unroll 4
        for (int v = 0; v < 32; ++v) {
            int o = t * 32 + v;
            int kk = o & 7, j = (o >> 3) & 15, kg = o >> 7;
            dst[o] = f2bf(src[(8 * kg + kk) * HD + ch * 16 + j]);
        }
    } else {
#pragma unroll 4
        for (int v = 0; v < 32; ++v) {
            int o = t * 32 + v;
            int kk = o & 7, j = (o >> 3) & 15, kg = o >> 7;
            dst[o] = (kg < 32) ? f2bf(Wsl[(8 * kg + kk) * NI + j]) : (unsigned short)0;
        }
    }
}

struct __align__(16) SMem {
    union {
        unsigned short h[BB * NI * ASH];  // 33792 B: bf16 h (wave-private per element)
        float slf[BB][NI * ASH / 2];      // slater scratch overlays own element's h
    } u;
    unsigned short gm[BB * HD];           // 2048 B: bf16 column means (wave-private)
};
static_assert(sizeof(SMem) == 35840, "3+ blocks/CU easily");

__global__ __launch_bounds__(256, 3)
void eqslater_mfma(const float* __restrict__ x0g,
                   const float* __restrict__ Win,
                   const float* __restrict__ bin,
                   const float* __restrict__ bmid,
                   const float* __restrict__ bsl,
                   const float* __restrict__ width,
                   const unsigned short* __restrict__ wtc,
                   float* __restrict__ out) {
    __shared__ SMem sm;
    const int tid = threadIdx.x;
    const int bbase = blockIdx.x * BB;
    const int e = tid >> 6;   // wave = element (fully independent waves)
    const int l = tid & 63;
    const int c = l & 15;     // h-row (B/C-col in transposed MFMA orientation)
    const int g = l >> 4;     // k-group; C rows 4g..4g+3 -> cols j = 16ch+4g+q
    const int j4 = 4 * g;

    // per-lane W fragment base: frag s of chunk fc at  wlane + fc*8192 + s*512
    const unsigned short* wlane = wtc + (size_t)g * 128 + (size_t)c * 8;

    bf16x8 bqA[8], bqB[8];
    // prologue: chunk 0 h-part frags (latency hides under input layer)
#pragma unroll
    for (int s = 0; s < 8; ++s)
        bqA[s] = *(const bf16x8*)(wlane + s * 512);

    // ---- input layer (wave-private): h = tanh(x0*W0 + gmean*W1 + b)
    {
        float x0v = x0g[(bbase + e) * NI + c];   // lane r holds x0[e][r] (dup x4)
        float ssum = x0v;
#pragma unroll
        for (int off = 8; off > 0; off >>= 1) ssum += __shfl_xor(ssum, off);
        const float gmean = ssum * 0.0625f;
        const int c4 = 4 * l;                    // this lane owns cols c4..c4+3
        float4 w0 = *(const float4*)&Win[c4];
        float4 w1 = *(const float4*)&Win[HD + c4];
        float4 bi = *(const float4*)&bin[c4];
        float g0 = __builtin_fmaf(gmean, w1.x, bi.x);
        float g1 = __builtin_fmaf(gmean, w1.y, bi.y);
        float g2 = __builtin_fmaf(gmean, w1.z, bi.z);
        float g3 = __builtin_fmaf(gmean, w1.w, bi.w);
#pragma unroll 4
        for (int r = 0; r < NI; ++r) {
            float xv = bcast(x0v, r);
            float f0 = tanh5(__builtin_fmaf(xv, w0.x, g0));
            float f1 = tanh5(__builtin_fmaf(xv, w0.y, g1));
            float f2 = tanh5(__builtin_fmaf(xv, w0.z, g2));
            float f3 = tanh5(__builtin_fmaf(xv, w0.w, g3));
            uint2 o; o.x = cvt_pk_bf16(f0, f1); o.y = cvt_pk_bf16(f2, f3);
            *(uint2*)&sm.u.h[(e * NI + r) * ASH + c4] = o;
        }
    }
    LGKM_WAIT();   // cross-lane h visibility within the wave

    bf16x8 af[8], agm[8];

#pragma unroll 1
    for (int layer = 0; layer < NMID; ++layer) {
        // ---- gm: column means of own h (lane owns cols 4l..4l+3)
        {
            const int c4 = 4 * l;
            float s0 = 0, s1 = 0, s2 = 0, s3 = 0;
#pragma unroll
            for (int r = 0; r < NI; ++r) {
                uint2 d = *(const uint2*)&sm.u.h[(e * NI + r) * ASH + c4];
                s0 += bflo(d.x); s1 += bfhi(d.x);
                s2 += bflo(d.y); s3 += bfhi(d.y);
            }
            uint2 go;
            go.x = cvt_pk_bf16(s0 * 0.0625f, s1 * 0.0625f);
            go.y = cvt_pk_bf16(s2 * 0.0625f, s3 * 0.0625f);
            *(uint2*)&sm.gm[e * HD + c4] = go;
        }
        LGKM_WAIT();   // gm visible to all lanes of this wave
        // A/B fragments: af = own h row c; agm = own gm (same for all c -> broadcast)
#pragma unroll
        for (int s = 0; s < 8; ++s) {
            af[s]  = *(const bf16x8*)&sm.u.h[(e * NI + c) * ASH + 32 * s + 8 * g];
            agm[s] = *(const bf16x8*)&sm.gm[e * HD + 32 * s + 8 * g];
        }
        const float* bml = bmid + layer * HD;

#pragma unroll 1
        for (int ch = 0; ch < 16; ++ch) {
            const int fc = layer * 16 + ch;
            const unsigned short* cb = wlane + (size_t)fc * 8192;

            // issue gm-part frag loads (consumed after h-part MFMA)
#pragma unroll
            for (int s = 0; s < 8; ++s)
                bqB[s] = *(const bf16x8*)(cb + 4096 + s * 512);

            // h-part GEMM: 8 MFMA with bqA (loaded last iteration)
            f32x4 p0 = {0.f,0.f,0.f,0.f}, p1 = {0.f,0.f,0.f,0.f};
#pragma unroll
            for (int s = 0; s < 4; ++s) {
                p0 = __builtin_amdgcn_mfma_f32_16x16x32_bf16(bqA[2 * s],     af[2 * s],     p0, 0, 0, 0);
                p1 = __builtin_amdgcn_mfma_f32_16x16x32_bf16(bqA[2 * s + 1], af[2 * s + 1], p1, 0, 0, 0);
            }
            // issue NEXT chunk's h-part loads (chunk fc+1; fc=47 -> slater chunk 48)
#pragma unroll
            for (int s = 0; s < 8; ++s)
                bqA[s] = *(const bf16x8*)(cb + 8192 + s * 512);

            // gm-part GEMM: own gvec lands in the same accumulator
#pragma unroll
            for (int s = 0; s < 4; ++s) {
                p0 = __builtin_amdgcn_mfma_f32_16x16x32_bf16(bqB[2 * s],     agm[2 * s],     p0, 0, 0, 0);
                p1 = __builtin_amdgcn_mfma_f32_16x16x32_bf16(bqB[2 * s + 1], agm[2 * s + 1], p1, 0, 0, 0);
            }
            f32x4 av = p0 + p1;

            // inline epilogue: C[j=16ch+4g+q][r=c];  h[c][j] = tanh(av+b) + h[c][j]
            const float4 bv = *(const float4*)&bml[ch * 16 + j4];
            unsigned short* hrow = &sm.u.h[(e * NI + c) * ASH + ch * 16 + j4];
            uint2 hd2 = *(const uint2*)hrow;
            float f0 = tanh5(av[0] + bv.x) + bflo(hd2.x);
            float f1 = tanh5(av[1] + bv.y) + bfhi(hd2.x);
            float f2 = tanh5(av[2] + bv.z) + bflo(hd2.y);
            float f3 = tanh5(av[3] + bv.w) + bfhi(hd2.y);
            uint2 w; w.x = cvt_pk_bf16(f0, f1); w.y = cvt_pk_bf16(f2, f3);
            *(uint2*)hrow = w;
        }
        LGKM_WAIT();   // epilogue h writes visible cross-lane for next gm pass
    }

    // ---- slater head: bqA already holds chunk 48 (Wsl) h-part frags
#pragma unroll
    for (int s = 0; s < 8; ++s)
        af[s] = *(const bf16x8*)&sm.u.h[(e * NI + c) * ASH + 32 * s + 8 * g];
    {
        f32x4 a0 = {0.f,0.f,0.f,0.f}, a1 = {0.f,0.f,0.f,0.f};
#pragma unroll
        for (int s = 0; s < 4; ++s) {
            a0 = __builtin_amdgcn_mfma_f32_16x16x32_bf16(bqA[2 * s],     af[2 * s],     a0, 0, 0, 0);
            a1 = __builtin_amdgcn_mfma_f32_16x16x32_bf16(bqA[2 * s + 1], af[2 * s + 1], a1, 0, 0, 0);
        }
        f32x4 sv = a0 + a1;   // lane (g,c): sl[row r=c][m=4g+q]
        const float4 bsv = *(const float4*)&bsl[j4];
        float* slp = &sm.u.slf[e][0];   // own-element region; own h now dead
        float4 o;
        o.x = sv[0] + bsv.x; o.y = sv[1] + bsv.y;
        o.z = sv[2] + bsv.z; o.w = sv[3] + bsv.w;
        *(float4*)&slp[c * SLS + j4] = o;
    }
    LGKM_WAIT();   // slf visible cross-lane within the wave

    // ---- per-wave slogdet: swap-free LU w/ partial pivoting (R11-verified)
    {
        const float* slp = &sm.u.slf[e][0];
        const int i = c;   // row, 4x duplicated across lanes
        float M[16];
#pragma unroll
        for (int jj = 0; jj < 4; ++jj) {
            float4 vv = *(const float4*)&slp[i * SLS + 4 * jj];
            M[4 * jj] = vv.x; M[4 * jj + 1] = vv.y; M[4 * jj + 2] = vv.z; M[4 * jj + 3] = vv.w;
        }

        int elim = 0;              // this lane's row already chosen as pivot
        unsigned chosen = 0;       // uniform: bitmask of chosen rows
        int invcnt = 0;            // uniform: inversion count of pivot sequence
        float dsign = 1.f, logabs = 0.f;
#pragma unroll
        for (int k = 0; k < 16; ++k) {
            float myv = elim ? -1.f : __builtin_fabsf(M[k]);
            float maxv = myv;
#pragma unroll
            for (int off = 8; off > 0; off >>= 1)
                maxv = fmaxf(maxv, __shfl_xor(maxv, off));
            unsigned long long bal = __ballot(myv == maxv);
            const int p = (__ffsll((long long)bal) - 1) & 15;   // lowest row w/ max

            invcnt += __popc(chosen >> (p + 1));
            chosen |= 1u << p;
            if (i == p) elim = 1;

            float piv = bcast(M[k], p);
            // NaN guard (singular matrix): finite logabs, no 0/0 poison.
            float ap = fmaxf(__builtin_fabsf(piv), 1e-35f);
            logabs += __logf(ap);
            if (piv < 0.f) dsign = -dsign;
            float spiv = __builtin_copysignf(ap, piv);
            float mi = __fdividef(M[k], spiv);
#pragma unroll
            for (int j = k + 1; j < 16; ++j) {
                float pr = bcast(M[j], p);
                if (!elim) M[j] = __builtin_fmaf(-mi, pr, M[j]);
            }
        }
        if (invcnt & 1) dsign = -dsign;

        float xv = (l < NI) ? x0g[(bbase + e) * NI + l] : 0.f;
        float sq = xv * xv;
#pragma unroll
        for (int off = 8; off > 0; off >>= 1) sq += __shfl_xor(sq, off);

        if (l == 0) {
            out[bbase + e] = dsign;
            out[BTOT + bbase + e] = logabs - HALF_LOGFACT - width[0] * sq;
        }
    }
}

extern "C" void kernel_launch(void* const* d_in, const int* in_sizes, int n_in,
                              void* d_out, int out_size, void* d_ws, size_t ws_size,
                              hipStream_t stream) {
    const float* x0   = (const float*)d_in[0];
    const float* Win  = (const float*)d_in[1];
    const float* bin  = (const float*)d_in[2];
    const float* Wmid = (const float*)d_in[3];
    const float* bmid = (const float*)d_in[4];
    const float* Wsl  = (const float*)d_in[5];
    const float* bsl  = (const float*)d_in[6];
    const float* wid  = (const float*)d_in[7];
    float* out = (float*)d_out;

    unsigned short* wtc = (unsigned short*)d_ws;   // 49 * 16384 B = 802816 B

    hipLaunchKernelGGL(prep_w, dim3(49), dim3(256), 0, stream, Wmid, Wsl, wtc);
    hipLaunchKernelGGL(eqslater_mfma, dim3(BTOT / BB), dim3(256), 0, stream,
                       x0, Win, bin, bmid, bsl, wid, wtc, out);
}

// Round 13
// 273.747 us; speedup vs baseline: 1.4566x; 1.4566x over previous
//
#include <hip/hip_runtime.h>

// Problem constants
#define BTOT 16384
#define NI   16
#define HD   256
#define BB   4            // elements per block; waves partition OUTPUT COLS (strips)
#define NMID 3
#define ASH  264          // h LDS row stride in bf16 (528B)
#define SLS  20           // slater scratch row stride (floats)
#define HALF_LOGFACT 15.3359295387f  // 0.5 * ln(16!)

typedef short  bf16x8 __attribute__((ext_vector_type(8)));
typedef float  f32x4  __attribute__((ext_vector_type(4)));

__device__ __forceinline__ unsigned short f2bf(float f) {   // prep kernel only
    unsigned u = __builtin_bit_cast(unsigned, f);
    u += 0x7FFFu + ((u >> 16) & 1u);
    return (unsigned short)(u >> 16);
}
__device__ __forceinline__ unsigned cvt_pk_bf16(float lo, float hi) {
    unsigned d;
    asm("v_cvt_pk_bf16_f32 %0, %1, %2" : "=v"(d) : "v"(lo), "v"(hi));
    return d;
}
__device__ __forceinline__ float bflo(unsigned u) { return __builtin_bit_cast(float, u << 16); }
__device__ __forceinline__ float bfhi(unsigned u) { return __builtin_bit_cast(float, u & 0xFFFF0000u); }
__device__ __forceinline__ float bcast(float x, int lane) {
    return __builtin_bit_cast(float,
        __builtin_amdgcn_readlane(__builtin_bit_cast(int, x), lane));
}
// tanh(x) = 1 - 2/(1 + 2^(x*2*log2(e))) : 5 VALU ops
__device__ __forceinline__ float tanh5(float x) {
    float z = __builtin_amdgcn_exp2f(x * 2.885390081777927f);
    return __builtin_fmaf(-2.0f, __builtin_amdgcn_rcpf(1.0f + z), 1.0f);
}
#define LGKM_BAR() do { asm volatile("s_waitcnt lgkmcnt(0)" ::: "memory"); \
    __builtin_amdgcn_s_barrier(); __builtin_amdgcn_sched_barrier(0); } while (0)
#define LGKM_WAIT() do { asm volatile("s_waitcnt lgkmcnt(0)" ::: "memory"); \
    __builtin_amdgcn_sched_barrier(0); } while (0)

// ---- prep: chunked fragment-order weights (verified R6-R12).
// Chunk fc<48: (layer=fc>>4, ch=fc&15): dst[kg*128 + j*8 + kk] = Wmid[layer][8kg+kk][ch*16+j],
//   kg in [0,64). Chunk 48: Wsl, kg in [0,32), rest zero.
__global__ void prep_w(const float* __restrict__ Wmid, const float* __restrict__ Wsl,
                       unsigned short* __restrict__ wtc) {
    const int b = blockIdx.x;       // 0..48
    const int t = threadIdx.x;
    unsigned short* dst = wtc + (size_t)b * 8192;
    if (b < 48) {
        const int layer = b >> 4, ch = b & 15;
        const float* src = Wmid + (size_t)layer * (2 * HD * HD);
#pragma unroll 4
        for (int v = 0; v < 32; ++v) {
            int o = t * 32 + v;
            int kk = o & 7, j = (o >> 3) & 15, kg = o >> 7;
            dst[o] = f2bf(src[(8 * kg + kk) * HD + ch * 16 + j]);
        }
    } else {
#pragma unroll 4
        for (int v = 0; v < 32; ++v) {
            int o = t * 32 + v;
            int kk = o & 7, j = (o >> 3) & 15, kg = o >> 7;
            dst[o] = (kg < 32) ? f2bf(Wsl[(8 * kg + kk) * NI + j]) : (unsigned short)0;
        }
    }
}

struct __align__(16) SMem {
    union {
        unsigned short h[BB * NI * ASH];  // 33792 B: bf16 h, shared across strips
        float slf[BB][NI * ASH / 2];      // slater scratch overlays element e's h
    } u;
    unsigned short gm[BB * HD];           // 2048 B: bf16 column means
};
static_assert(sizeof(SMem) == 35840, "LDS fine");

__global__ __launch_bounds__(256, 2)
void eqslater_mfma(const float* __restrict__ x0g,
                   const float* __restrict__ Win,
                   const float* __restrict__ bin,
                   const float* __restrict__ bmid,
                   const float* __restrict__ bsl,
                   const float* __restrict__ width,
                   const unsigned short* __restrict__ wtc,
                   float* __restrict__ out) {
    __shared__ SMem sm;
    const int tid = threadIdx.x;
    const int bbase = blockIdx.x * BB;
    const int w = tid >> 6;   // wave = output-column STRIP [64w, 64w+64)
    const int l = tid & 63;
    const int c = l & 15;     // A-row (chunk-local j) / B-col (h-row) / C-col
    const int g = l >> 4;     // k-group; C rows 4g..4g+3 -> cols j = 16ch+4g+q
    const int j4 = 4 * g;
    const int B0 = 64 * w;    // strip base column

    const unsigned short* wlane = wtc + (size_t)g * 128 + (size_t)c * 8;

    // ---- x0 + per-element means (lane l holds x0[el=l>>4][r=l&15])
    float x0v = x0g[bbase * NI + l];
    {
        float ssum = x0v;
#pragma unroll
        for (int off = 8; off > 0; off >>= 1) ssum += __shfl_xor(ssum, off);
        // lanes of group el hold gmean[el]
        x0v = x0v;  // keep
        // input layer: lane owns column jc = B0 + l for ALL (el, r)
        const float gme = ssum * 0.0625f;
        const int jc = B0 + l;
        const float w0 = Win[jc], w1 = Win[HD + jc], bj = bin[jc];
#pragma unroll
        for (int el = 0; el < 4; ++el) {
            float ge = bcast(gme, el * 16);
            float gl = __builtin_fmaf(ge, w1, bj);
#pragma unroll 4
            for (int r = 0; r < NI; ++r) {
                float xv = bcast(x0v, el * 16 + r);
                float f = tanh5(__builtin_fmaf(xv, w0, gl));
                sm.u.h[(el * NI + r) * ASH + jc] =
                    (unsigned short)cvt_pk_bf16(f, f);
            }
        }
    }
    LGKM_BAR();   // h complete (all strips)

    bf16x8 afE[4][8], agm[8], wf[8];

#pragma unroll 1
    for (int layer = 0; layer < NMID; ++layer) {
        // ---- B-frags for all 4 elements (pre-layer h) -> registers
#pragma unroll
        for (int el = 0; el < 4; ++el)
#pragma unroll
            for (int s = 0; s < 8; ++s)
                afE[el][s] = *(const bf16x8*)&sm.u.h[(el * NI + c) * ASH + 32 * s + 8 * g];
        // ---- gm pass: lane (el2 = l>>4) sums 4 cols (uint2) of its strip
        {
            const int el2 = l >> 4;
            const int c0 = B0 + (l & 15) * 4;
            float s0 = 0, s1 = 0, s2 = 0, s3 = 0;
#pragma unroll
            for (int r = 0; r < NI; ++r) {
                uint2 d = *(const uint2*)&sm.u.h[(el2 * NI + r) * ASH + c0];
                s0 += bflo(d.x); s1 += bfhi(d.x);
                s2 += bflo(d.y); s3 += bfhi(d.y);
            }
            uint2 go;
            go.x = cvt_pk_bf16(s0 * 0.0625f, s1 * 0.0625f);
            go.y = cvt_pk_bf16(s2 * 0.0625f, s3 * 0.0625f);
            *(uint2*)&sm.gm[el2 * HD + c0] = go;
        }
        LGKM_BAR();   // gm complete; afE snapshots taken before any epilogue write
        // replicated-gm B frags (B col r = gm of element r&3)
#pragma unroll
        for (int s = 0; s < 8; ++s)
            agm[s] = *(const bf16x8*)&sm.gm[(c & 3) * HD + 32 * s + 8 * g];

        const float* bml = bmid + layer * HD;

#pragma unroll 1
        for (int cc = 0; cc < 4; ++cc) {
            const int ch = 4 * w + cc;          // this wave's chunk
            const int fc = layer * 16 + ch;
            const unsigned short* cb = wlane + (size_t)fc * 8192;

            // gm-part W frags first; gvec(+bias) for ALL 4 elements in one pass
#pragma unroll
            for (int s = 0; s < 8; ++s)
                wf[s] = *(const bf16x8*)(cb + 4096 + s * 512);
            f32x4 accG = {0.f, 0.f, 0.f, 0.f};
#pragma unroll
            for (int s = 0; s < 8; ++s)
                accG = __builtin_amdgcn_mfma_f32_16x16x32_bf16(wf[s], agm[s], accG, 0, 0, 0);
            const float4 bv = *(const float4*)&bml[ch * 16 + j4];
            accG[0] += bv.x; accG[1] += bv.y; accG[2] += bv.z; accG[3] += bv.w;

            // h-part W frags (reuse wf regs; gm-MFMAs already consumed them)
#pragma unroll
            for (int s = 0; s < 8; ++s)
                wf[s] = *(const bf16x8*)(cb + s * 512);

            // per element: fetch its gvec via lane-swap, 8 MFMA, inline epilogue
#pragma unroll
            for (int el = 0; el < 4; ++el) {
                // gvec[el][16ch+4g+q] lives in lane (g, c=el), reg q
                const int src = (l & 48) + el;
                float gv0 = __shfl(accG[0], src);
                float gv1 = __shfl(accG[1], src);
                float gv2 = __shfl(accG[2], src);
                float gv3 = __shfl(accG[3], src);
                f32x4 acc = {0.f, 0.f, 0.f, 0.f};
#pragma unroll
                for (int s = 0; s < 8; ++s)
                    acc = __builtin_amdgcn_mfma_f32_16x16x32_bf16(wf[s], afE[el][s], acc, 0, 0, 0);
                unsigned short* hrow = &sm.u.h[(el * NI + c) * ASH + ch * 16 + j4];
                uint2 hd2 = *(const uint2*)hrow;
                float f0 = tanh5(acc[0] + gv0) + bflo(hd2.x);
                float f1 = tanh5(acc[1] + gv1) + bfhi(hd2.x);
                float f2 = tanh5(acc[2] + gv2) + bflo(hd2.y);
                float f3 = tanh5(acc[3] + gv3) + bfhi(hd2.y);
                uint2 wo; wo.x = cvt_pk_bf16(f0, f1); wo.y = cvt_pk_bf16(f2, f3);
                *(uint2*)hrow = wo;
            }
        }
        LGKM_BAR();   // all strips' epilogue writes visible for next layer
    }

    // ---- slater head: wave e = w owns element e; Wsl frags from global (chunk 48)
    {
        const int e = w;
        bf16x8 afs[8];
#pragma unroll
        for (int s = 0; s < 8; ++s)
            afs[s] = *(const bf16x8*)&sm.u.h[(e * NI + c) * ASH + 32 * s + 8 * g];
        const unsigned short* cb = wlane + (size_t)48 * 8192;
        f32x4 a0 = {0.f,0.f,0.f,0.f}, a1 = {0.f,0.f,0.f,0.f};
#pragma unroll
        for (int s = 0; s < 4; ++s) {
            bf16x8 b0 = *(const bf16x8*)(cb + (2 * s) * 512);
            bf16x8 b1 = *(const bf16x8*)(cb + (2 * s + 1) * 512);
            a0 = __builtin_amdgcn_mfma_f32_16x16x32_bf16(b0, afs[2 * s],     a0, 0, 0, 0);
            a1 = __builtin_amdgcn_mfma_f32_16x16x32_bf16(b1, afs[2 * s + 1], a1, 0, 0, 0);
        }
        f32x4 sv = a0 + a1;   // lane (g,c): sl[row r=c][m=4g+q]
        const float4 bsv = *(const float4*)&bsl[j4];
        float* slp = &sm.u.slf[e][0];   // overlays own element's h (now dead)
        float4 o;
        o.x = sv[0] + bsv.x; o.y = sv[1] + bsv.y;
        o.z = sv[2] + bsv.z; o.w = sv[3] + bsv.w;
        *(float4*)&slp[c * SLS + j4] = o;
    }
    LGKM_WAIT();   // in-wave: slf visible

    // ---- per-wave slogdet: swap-free LU w/ partial pivoting (R11/R12-verified)
    {
        const int e = w;
        const float* slp = &sm.u.slf[e][0];
        const int i = c;
        float M[16];
#pragma unroll
        for (int jj = 0; jj < 4; ++jj) {
            float4 vv = *(const float4*)&slp[i * SLS + 4 * jj];
            M[4 * jj] = vv.x; M[4 * jj + 1] = vv.y; M[4 * jj + 2] = vv.z; M[4 * jj + 3] = vv.w;
        }

        int elim = 0;
        unsigned chosen = 0;
        int invcnt = 0;
        float dsign = 1.f, logabs = 0.f;
#pragma unroll
        for (int k = 0; k < 16; ++k) {
            float myv = elim ? -1.f : __builtin_fabsf(M[k]);
            float maxv = myv;
#pragma unroll
            for (int off = 8; off > 0; off >>= 1)
                maxv = fmaxf(maxv, __shfl_xor(maxv, off));
            unsigned long long bal = __ballot(myv == maxv);
            const int p = (__ffsll((long long)bal) - 1) & 15;

            invcnt += __popc(chosen >> (p + 1));
            chosen |= 1u << p;
            if (i == p) elim = 1;

            float piv = bcast(M[k], p);
            float ap = fmaxf(__builtin_fabsf(piv), 1e-35f);
            logabs += __logf(ap);
            if (piv < 0.f) dsign = -dsign;
            float spiv = __builtin_copysignf(ap, piv);
            float mi = __fdividef(M[k], spiv);
#pragma unroll
            for (int j = k + 1; j < 16; ++j) {
                float pr = bcast(M[j], p);
                if (!elim) M[j] = __builtin_fmaf(-mi, pr, M[j]);
            }
        }
        if (invcnt & 1) dsign = -dsign;

        float xv = (l < NI) ? x0g[(bbase + w) * NI + l] : 0.f;
        float sq = xv * xv;
#pragma unroll
        for (int off = 8; off > 0; off >>= 1) sq += __shfl_xor(sq, off);

        if (l == 0) {
            out[bbase + w] = dsign;
            out[BTOT + bbase + w] = logabs - HALF_LOGFACT - width[0] * sq;
        }
    }
}

extern "C" void kernel_launch(void* const* d_in, const int* in_sizes, int n_in,
                              void* d_out, int out_size, void* d_ws, size_t ws_size,
                              hipStream_t stream) {
    const float* x0   = (const float*)d_in[0];
    const float* Win  = (const float*)d_in[1];
    const float* bin  = (const float*)d_in[2];
    const float* Wmid = (const float*)d_in[3];
    const float* bmid = (const float*)d_in[4];
    const float* Wsl  = (const float*)d_in[5];
    const float* bsl  = (const float*)d_in[6];
    const float* wid  = (const float*)d_in[7];
    float* out = (float*)d_out;

    unsigned short* wtc = (unsigned short*)d_ws;   // 49 * 16384 B = 802816 B

    hipLaunchKernelGGL(prep_w, dim3(49), dim3(256), 0, stream, Wmid, Wsl, wtc);
    hipLaunchKernelGGL(eqslater_mfma, dim3(BTOT / BB), dim3(256), 0, stream,
                       x0, Win, bin, bmid, bsl, wid, wtc, out);
}